// Round 1
// baseline (372.614 us; speedup 1.0000x reference)
//
#include <hip/hip_runtime.h>

// CondLaneHead dynamic mask head, fp32 baseline.
// N=4 imgs, 8 inst/img -> 32 instances; C=64, CIN=66, H=160, W=256, L=40960.
// out[1][32][160][256] fp32.
//
// Params per instance (8513 floats):
//   [0:4224)    w0 (64 x 66)   row-major o*66+c
//   [4224:8320) w1 (64 x 64)   row-major o*64+c
//   [8320:8384) w2 (1 x 64)
//   [8384:8448) b0
//   [8448:8512) b1
//   [8512]      b2  (minus 2.19 mask bias shift)
//
// Workspace layout per instance (stride 8704 floats):
//   [0:4224)    w0T (66 x 64)  c*64+o   (c=0: loc_x, c=1: loc_y, c>=2: x ch)
//   [4224:8320) w1T (64 x 64)  c*64+o
//   [8320:8384) w2
//   [8384:8448) b0
//   [8448:8512) b1
//   [8512]      b2 - 2.19

#define NP   8513
#define WST  8704
#define HW   40960
#define CC   64

__global__ void condlane_prep(const float* __restrict__ params,
                              float* __restrict__ wt) {
  const int inst = blockIdx.x;
  const float* __restrict__ p = params + inst * NP;
  float* __restrict__ o = wt + inst * WST;
  // w0 transpose: dest[c*64+r] = src[r*66+c]
  for (int idx = threadIdx.x; idx < 4224; idx += 256) {
    const int c = idx >> 6, r = idx & 63;
    o[idx] = p[r * 66 + c];
  }
  // w1 transpose: dest[c*64+r] = src[r*64+c]
  for (int idx = threadIdx.x; idx < 4096; idx += 256) {
    const int c = idx >> 6, r = idx & 63;
    o[4224 + idx] = p[4224 + r * 64 + c];
  }
  // w2, b0, b1, b2 straight copy (193 floats), fold the -2.19 mask bias shift
  for (int idx = threadIdx.x; idx < 193; idx += 256) {
    float v = p[8320 + idx];
    if (idx == 192) v -= 2.19f;
    o[8320 + idx] = v;
  }
}

__global__ __launch_bounds__(256, 3) void condlane_main(
    const float* __restrict__ x, const float* __restrict__ wt,
    float* __restrict__ out) {
  const int inst = blockIdx.y;                 // 0..31
  const int p = blockIdx.x * 256 + threadIdx.x;  // 0..40959
  const float* __restrict__ wp = wt + inst * WST;   // block-uniform -> s_load
  const float* __restrict__ xp = x + (inst >> 3) * (CC * HW) + p;
  const float fx = (float)(p & 255);   // loc_x (W=256)
  const float fy = (float)(p >> 8);    // loc_y

  // ---- layer 1: h = b0 + w0 @ [loc_x, loc_y, x...] ----
  float h[64];
#pragma unroll
  for (int o = 0; o < 64; o++)
    h[o] = wp[8384 + o] + wp[o] * fx + wp[64 + o] * fy;

#pragma unroll 4
  for (int c = 0; c < 64; c++) {
    const float f = xp[c * HW];                       // coalesced across lanes
    const float* __restrict__ wr = wp + (c + 2) * 64; // uniform -> SGPR
#pragma unroll
    for (int o = 0; o < 64; o++) h[o] = fmaf(wr[o], f, h[o]);
  }

  // ---- layer 2: h2 = b1 + w1 @ relu(h) ----
  float h2[64];
#pragma unroll
  for (int o = 0; o < 64; o++) h2[o] = wp[8448 + o];

#pragma unroll 4
  for (int c = 0; c < 64; c++) {
    const float f = fmaxf(h[c], 0.0f);
    const float* __restrict__ wr = wp + 4224 + c * 64;
#pragma unroll
    for (int o = 0; o < 64; o++) h2[o] = fmaf(wr[o], f, h2[o]);
  }

  // ---- layer 3: out = (b2 - 2.19) + w2 . relu(h2) ----
  float acc = wp[8512];
#pragma unroll
  for (int c = 0; c < 64; c++)
    acc = fmaf(wp[8320 + c], fmaxf(h2[c], 0.0f), acc);

  out[inst * HW + p] = acc;
}

extern "C" void kernel_launch(void* const* d_in, const int* in_sizes, int n_in,
                              void* d_out, int out_size, void* d_ws, size_t ws_size,
                              hipStream_t stream) {
  const float* x      = (const float*)d_in[0];  // [4,64,160,256] fp32
  const float* params = (const float*)d_in[1];  // [32,8513] fp32
  // d_in[2] = num_ins (static, all 8) -- mapping inst>>3 hardcoded
  float* wt  = (float*)d_ws;                    // needs 32*8704*4 = 1,114,112 B
  float* out = (float*)d_out;

  condlane_prep<<<32, 256, 0, stream>>>(params, wt);
  condlane_main<<<dim3(160, 32), 256, 0, stream>>>(x, wt, out);
}